// Round 12
// baseline (283.041 us; speedup 1.0000x reference)
//
#include <hip/hip_runtime.h>

// TripletAngularMarginLoss: bs=16384, d=64 (== number of classes)
// out = mean(relu(0.5 + ap - an)) + mean(relu(0.8-ap)) + mean(relu(an-0.4)) + CE
// ap[i] = min_{t[j]==t[i]} cos(x_i,x_j), an[i] = max_{t[j]!=t[i]} cos(x_i,x_j)
//
// R10 ledger: VALU cycles/SIMD constant ~180K across R7/R9/R10; only sorted-R8
// reduced them. Theory: SIMD issue-port saturated (VALU+SALU+DS+accvgpr moves
// from the 32-arch-VGPR split). R11 = R8's sorted mining done right:
//  - rows AND cols class-sorted -> wave-uniform pure-neg fast path (8 v_max/jc)
//  - launch_bounds(256,4): ~64 arch VGPRs, mining state stays arch (no AGPR tax)
//  - plumbing: 3 graph nodes (R8 had 6 + a 38us serial scan). hist/cursor/done
//    init via 0xAA-poison-subtract (P read from reserved ws word); per-block
//    redundant wave-shuffle scan; finalize folded into mine's last block.

#define N_ROWS 16384
#define N_DIM 64
#define N_CLS 64

typedef __attribute__((ext_vector_type(8))) short bf16x8;
typedef __attribute__((ext_vector_type(8))) unsigned short ushort8;
typedef __attribute__((ext_vector_type(4))) float f32x4;

__device__ inline unsigned short f2bf(float f) {
  unsigned u = __float_as_uint(f);
  unsigned r = u + 0x7fffu + ((u >> 16) & 1u);   // round-to-nearest-even
  return (unsigned short)(r >> 16);
}

// order-preserving float->uint encoding for atomicMin/atomicMax
__device__ inline unsigned enc_key(float f) {
  unsigned u = __float_as_uint(f);
  return (u & 0x80000000u) ? ~u : (u | 0x80000000u);
}
__device__ inline float dec_key(unsigned k) {
  unsigned u = (k & 0x80000000u) ? (k ^ 0x80000000u) : ~k;
  return __uint_as_float(u);
}

// async global->LDS DMA, 16B per lane, dest = lds_base + lane*16 (linear)
__device__ inline void g2lds16(const void* g, void* l) {
  __builtin_amdgcn_global_load_lds(
      (const __attribute__((address_space(1))) void*)g,
      (__attribute__((address_space(3))) void*)l, 16, 0, 0);
}

// ---------------- Kernel A: normalize, bf16 copy, per-row CE, class histogram
__global__ void prep_kernel(const float* __restrict__ x, const int* __restrict__ tgt,
                            unsigned short* __restrict__ xb, float* __restrict__ ce_row,
                            unsigned* __restrict__ mp_key, unsigned* __restrict__ mn_key,
                            unsigned* __restrict__ hist) {
  const int row  = blockIdx.x * 4 + (threadIdx.x >> 6);
  const int lane = threadIdx.x & 63;
  float v  = x[row * N_DIM + lane];
  float ss = v * v;
#pragma unroll
  for (int s = 1; s < 64; s <<= 1) ss += __shfl_xor(ss, s, 64);
  float xn = v * rsqrtf(ss);
  xb[row * N_DIM + lane] = f2bf(xn);

  float mx = xn;
#pragma unroll
  for (int s = 1; s < 64; s <<= 1) mx = fmaxf(mx, __shfl_xor(mx, s, 64));
  float e  = __expf(xn - mx);
  float se = e;
#pragma unroll
  for (int s = 1; s < 64; s <<= 1) se += __shfl_xor(se, s, 64);
  float lse = mx + __logf(se);
  int   t   = tgt[row];                 // wave-uniform
  float xt  = __shfl(xn, t, 64);
  if (lane == 0) {
    ce_row[row] = lse - xt;
    mp_key[row] = 0xFFFFFFFFu;          // +inf key for atomicMin
    mn_key[row] = 0u;                   // -inf key for atomicMax
    atomicAdd(&hist[t], 1u);            // counts on top of poison base P
  }
}

// ---------------- Kernel A2: scatter rows into class-sorted order ------------
// Per block: 64-lane shuffle scan of (hist - P) -> exclusive bases (redundant,
// cheap); then 8 lanes/row copy, rank via atomicAdd(cursor)-P.
__global__ void scatter_kernel(const unsigned short* __restrict__ xb, const int* __restrict__ tgt,
                               const unsigned* __restrict__ hist, unsigned* __restrict__ cursor,
                               const unsigned* __restrict__ pz, unsigned* __restrict__ done,
                               unsigned short* __restrict__ xbs, unsigned short* __restrict__ tgs) {
  __shared__ unsigned sbase[N_CLS];
  const unsigned P = pz[0];             // poison word (ws never written here)
  if (threadIdx.x < 64) {
    const int lane = threadIdx.x;
    unsigned v = hist[lane] - P;        // true count
    unsigned incl = v;
#pragma unroll
    for (int s = 1; s < 64; s <<= 1) {
      unsigned o = __shfl_up(incl, s, 64);
      if (lane >= s) incl += o;
    }
    sbase[lane] = incl - v;             // exclusive prefix
  }
  __syncthreads();

  const int lane = threadIdx.x & 63;
  const int sub  = lane & 7;
  const int row  = blockIdx.x * 32 + (threadIdx.x >> 6) * 8 + (lane >> 3);
  const int c    = tgt[row];
  unsigned dst = 0;
  if (sub == 0) dst = sbase[c] + (atomicAdd(&cursor[c], 1u) - P);
  dst = __shfl(dst, lane & 56, 64);     // broadcast from group leader
  ((ushort8*)xbs)[dst * 8 + sub] = ((const ushort8*)xb)[row * 8 + sub];
  if (sub == 0) tgs[dst] = (unsigned short)c;
}

// ---------------- Kernel B: sorted MFMA mining + last-block finalize ---------
// grid = 128 i-blocks * 16 j-splits = 2048 blocks of 256 threads (4 waves).
// launch_bounds(256,4): 128-reg budget -> mining state stays in arch VGPRs.
// LDS-staged B (R7 structure: 4-tile phases, dbuf, XOR-swizzle, unroll-1 j4).
// Sorted rows+cols: per tile, wave-uniform branch on class-range overlap:
// disjoint -> 8 v_max; all-same -> 8 v_min; mixed (rare) -> full compare path.
__global__ __launch_bounds__(256, 4)
void mine_kernel(const unsigned short* __restrict__ xbs, const unsigned short* __restrict__ tgs,
                 unsigned* __restrict__ mp_key, unsigned* __restrict__ mn_key,
                 const float* __restrict__ ce_row, const unsigned* __restrict__ pz,
                 unsigned* __restrict__ done, float* __restrict__ out) {
  __shared__ unsigned short Bt[2][4][1024];   // 2 bufs x 4 tiles x 2KB, swizzled
  __shared__ unsigned short tjl[N_ROWS / 16]; // 2KB classes of this j-range
  __shared__ float red[4];
  __shared__ bool  last;

  const int lane    = threadIdx.x & 63;
  const int wv      = threadIdx.x >> 6;
  const int iblk    = blockIdx.x >> 4;
  const int jspl    = blockIdx.x & 15;
  const int rowbase = iblk * 128 + wv * 32;
  const int m = lane & 15, q = lane >> 4;
  const int jbase = jspl * (N_ROWS / 16);

  bf16x8 a[2][2];
#pragma unroll
  for (int tr = 0; tr < 2; ++tr) {
    const unsigned short* p = xbs + (rowbase + tr * 16 + m) * N_DIM + q * 8;
    a[tr][0] = *(const bf16x8*)(p);
    a[tr][1] = *(const bf16x8*)(p + 32);
  }
  // packed classes of owned C/D rows (row = tr*16+q*4+r), 8b each
  unsigned tip[2];
#pragma unroll
  for (int tr = 0; tr < 2; ++tr) {
    unsigned vv = 0;
#pragma unroll
    for (int r = 0; r < 4; ++r)
      vv |= ((unsigned)tgs[rowbase + tr * 16 + q * 4 + r] & 0xffu) << (8 * r);
    tip[tr] = vv;
  }
  const int clo = __builtin_amdgcn_readfirstlane((int)tgs[rowbase]);
  const int chi = __builtin_amdgcn_readfirstlane((int)tgs[rowbase + 31]);

  float mp[8], mn[8];
#pragma unroll
  for (int k = 0; k < 8; ++k) { mp[k] = __builtin_inff(); mn[k] = -__builtin_inff(); }

  for (int k = threadIdx.x; k < N_ROWS / 16; k += 256) tjl[k] = tgs[jbase + k];

  const unsigned short* src0 =
      xbs + (jbase + (lane >> 3)) * N_DIM + (((lane & 7) ^ ((lane >> 3) & 7)) * 8);

#define STAGE(P_, BUF)                                                           \
  do {                                                                           \
    const unsigned short* s_ = src0 + ((P_) * 64 + wv * 16) * N_DIM;             \
    g2lds16(s_,             (unsigned short*)&Bt[(BUF)][wv][0] + lane * 8);      \
    g2lds16(s_ + 8 * N_DIM, (unsigned short*)&Bt[(BUF)][wv][0] + 512 + lane * 8);\
  } while (0)

  STAGE(0, 0);
  __syncthreads();

  const int roff0 = m * 128 + ((q * 16) ^ ((m & 7) << 4));
  const int roff1 = m * 128 + (((64) + q * 16) ^ ((m & 7) << 4));

  for (int ph = 0; ph < 16; ++ph) {
    const int pb = ph & 1;
    if (ph < 15) STAGE(ph + 1, pb ^ 1);
#pragma unroll 1
    for (int j4 = 0; j4 < 4; ++j4) {
      const int jc = ph * 4 + j4;
      const char* bb = (const char*)&Bt[pb][j4][0];
      const bf16x8 cb0 = *(const bf16x8*)(bb + roff0);
      const bf16x8 cb1 = *(const bf16x8*)(bb + roff1);
      const int tlo = __builtin_amdgcn_readfirstlane((int)tjl[jc * 16]);
      const int thi = __builtin_amdgcn_readfirstlane((int)tjl[jc * 16 + 15]);

      f32x4 acc0 = {0.f, 0.f, 0.f, 0.f}, acc1 = {0.f, 0.f, 0.f, 0.f};
      acc0 = __builtin_amdgcn_mfma_f32_16x16x32_bf16(a[0][0], cb0, acc0, 0, 0, 0);
      acc0 = __builtin_amdgcn_mfma_f32_16x16x32_bf16(a[0][1], cb1, acc0, 0, 0, 0);
      acc1 = __builtin_amdgcn_mfma_f32_16x16x32_bf16(a[1][0], cb0, acc1, 0, 0, 0);
      acc1 = __builtin_amdgcn_mfma_f32_16x16x32_bf16(a[1][1], cb1, acc1, 0, 0, 0);

      if (thi < clo || tlo > chi) {          // pure negative (dominant)
#pragma unroll
        for (int r = 0; r < 4; ++r) {
          mn[r]     = fmaxf(mn[r],     acc0[r]);
          mn[4 + r] = fmaxf(mn[4 + r], acc1[r]);
        }
      } else if (clo == chi && tlo == thi && tlo == clo) {   // pure positive
#pragma unroll
        for (int r = 0; r < 4; ++r) {
          mp[r]     = fminf(mp[r],     acc0[r]);
          mp[4 + r] = fminf(mp[4 + r], acc1[r]);
        }
      } else {                                // boundary tile (rare)
        const unsigned ctj = (unsigned)tjl[jc * 16 + m] & 0xffu;
#pragma unroll
        for (int tr = 0; tr < 2; ++tr) {
          const f32x4 ac = tr ? acc1 : acc0;
#pragma unroll
          for (int r = 0; r < 4; ++r) {
            const bool  pos = (((tip[tr] >> (8 * r)) & 0xffu) == ctj);
            const float d   = ac[r];
            const int   k   = tr * 4 + r;
            mp[k] = fminf(mp[k], pos ? d : __builtin_inff());
            mn[k] = fmaxf(mn[k], pos ? -__builtin_inff() : d);
          }
        }
      }
    }
    __syncthreads();
  }
#undef STAGE

#pragma unroll
  for (int s = 1; s < 16; s <<= 1) {
#pragma unroll
    for (int k = 0; k < 8; ++k) {
      mp[k] = fminf(mp[k], __shfl_xor(mp[k], s, 64));
      mn[k] = fmaxf(mn[k], __shfl_xor(mn[k], s, 64));
    }
  }
  if (m == 0) {
#pragma unroll
    for (int tr = 0; tr < 2; ++tr)
#pragma unroll
      for (int r = 0; r < 4; ++r) {
        const int row = rowbase + tr * 16 + q * 4 + r;   // sorted index: means
        atomicMin(&mp_key[row], enc_key(mp[tr * 4 + r]));  // are perm-invariant
        atomicMax(&mn_key[row], enc_key(mn[tr * 4 + r]));
      }
  }

  // ---- last-block finalize (saves a kernel launch) ----
  __syncthreads();                       // drains this block's atomics (vmcnt)
  if (threadIdx.x == 0) {
    __threadfence();
    unsigned old = atomicAdd(done, 1u);
    last = (old == pz[0] + (unsigned)gridDim.x - 1u);
  }
  __syncthreads();
  if (!last) return;

  float s = 0.f;
  for (int i = threadIdx.x; i < N_ROWS; i += 256) {
    unsigned kp = __hip_atomic_load(&mp_key[i], __ATOMIC_RELAXED, __HIP_MEMORY_SCOPE_AGENT);
    unsigned kn = __hip_atomic_load(&mn_key[i], __ATOMIC_RELAXED, __HIP_MEMORY_SCOPE_AGENT);
    float ce = __hip_atomic_load(&ce_row[i], __ATOMIC_RELAXED, __HIP_MEMORY_SCOPE_AGENT);
    float ap = dec_key(kp), an = dec_key(kn);
    s += fmaxf(0.5f + ap - an, 0.f) + fmaxf(0.8f - ap, 0.f) +
         fmaxf(an - 0.4f, 0.f) + ce;
  }
#pragma unroll
  for (int sh = 1; sh < 64; sh <<= 1) s += __shfl_xor(s, sh, 64);
  if (lane == 0) red[wv] = s;
  __syncthreads();
  if (threadIdx.x == 0)
    out[0] = (red[0] + red[1] + red[2] + red[3]) * (1.0f / N_ROWS);
}

extern "C" void kernel_launch(void* const* d_in, const int* in_sizes, int n_in,
                              void* d_out, int out_size, void* d_ws, size_t ws_size,
                              hipStream_t stream) {
  const float* x   = (const float*)d_in[0];
  const int*   tgt = (const int*)d_in[1];
  char* ws = (char*)d_ws;

  unsigned short* xb     = (unsigned short*)ws;                              // 2 MB
  unsigned short* xbs    = (unsigned short*)(ws + (2u << 20));               // 2 MB sorted
  unsigned*       mp_key = (unsigned*)(ws + (4u << 20));                     // 64 KB
  unsigned*       mn_key = (unsigned*)(ws + (4u << 20) + (64u << 10));       // 64 KB
  float*          ce_row = (float*)(ws + (4u << 20) + (128u << 10));         // 64 KB
  unsigned short* tgs    = (unsigned short*)(ws + (4u << 20) + (192u << 10));// 32 KB
  unsigned*       hist   = (unsigned*)(ws + (4u << 20) + (224u << 10));      // 256 B (poison base)
  unsigned*       cursor = hist + 64;                                        // 256 B (poison base)
  unsigned*       done   = cursor + 64;                                      // 4 B  (poison base)
  unsigned*       pz     = done + 1;                                         // reserved, never written
  float*          out    = (float*)d_out;

  prep_kernel<<<N_ROWS / 4, 256, 0, stream>>>(x, tgt, xb, ce_row, mp_key, mn_key, hist);
  scatter_kernel<<<N_ROWS / 32, 256, 0, stream>>>(xb, tgt, hist, cursor, pz, done, xbs, tgs);
  mine_kernel<<<(N_ROWS / 128) * 16, 256, 0, stream>>>(xbs, tgs, mp_key, mn_key,
                                                       ce_row, pz, done, out);
}

// Round 13
// 199.580 us; speedup vs baseline: 1.4182x; 1.4182x over previous
//
#include <hip/hip_runtime.h>

// TripletAngularMarginLoss: bs=16384, d=64 (== number of classes)
// out = mean(relu(0.5 + ap - an)) + mean(relu(0.8-ap)) + mean(relu(an-0.4)) + CE
// ap[i] = min_{t[j]==t[i]} cos(x_i,x_j), an[i] = max_{t[j]!=t[i]} cos(x_i,x_j)
//
// R12 ledger: issue-count theory dead (sorted 8-op fast path: no mine speedup).
// All pipes <30% busy, wall 4x max-pipe floor -> DEPENDENCY-latency-bound:
// per jc, mining reads acc right after the MFMA chain (full lgkm+MFMA latency
// stall), and unroll-1 hides nothing across iterations. R13: explicit 2-slot
// software pipeline - MFMA(jc) issues, MINE(jc-1) executes under its latency;
// carry crosses the phase barrier in registers. launch_bounds(256,6) = ~85-reg
// budget for the ~72-reg live set (no R6-style explosion, no AGPR split).

#define N_ROWS 16384
#define N_DIM 64

typedef __attribute__((ext_vector_type(8))) short bf16x8;
typedef __attribute__((ext_vector_type(4))) float f32x4;

__device__ inline unsigned short f2bf(float f) {
  unsigned u = __float_as_uint(f);
  unsigned r = u + 0x7fffu + ((u >> 16) & 1u);   // round-to-nearest-even
  return (unsigned short)(r >> 16);
}

// order-preserving float->uint encoding for atomicMin/atomicMax
__device__ inline unsigned enc_key(float f) {
  unsigned u = __float_as_uint(f);
  return (u & 0x80000000u) ? ~u : (u | 0x80000000u);
}
__device__ inline float dec_key(unsigned k) {
  unsigned u = (k & 0x80000000u) ? (k ^ 0x80000000u) : ~k;
  return __uint_as_float(u);
}

// async global->LDS DMA, 16B per lane, dest = lds_base + lane*16 (linear)
__device__ inline void g2lds16(const void* g, void* l) {
  __builtin_amdgcn_global_load_lds(
      (const __attribute__((address_space(1))) void*)g,
      (__attribute__((address_space(3))) void*)l, 16, 0, 0);
}

// ---------------- Kernel A: normalize rows, emit bf16 copy, per-row CE -------
__global__ void prep_kernel(const float* __restrict__ x, const int* __restrict__ tgt,
                            unsigned short* __restrict__ xb, float* __restrict__ ce_row,
                            unsigned* __restrict__ mp_key, unsigned* __restrict__ mn_key,
                            float* __restrict__ out) {
  const int row  = blockIdx.x * 4 + (threadIdx.x >> 6);
  const int lane = threadIdx.x & 63;
  float v  = x[row * N_DIM + lane];
  float ss = v * v;
#pragma unroll
  for (int s = 1; s < 64; s <<= 1) ss += __shfl_xor(ss, s, 64);
  float xn = v * rsqrtf(ss);
  xb[row * N_DIM + lane] = f2bf(xn);

  float mx = xn;
#pragma unroll
  for (int s = 1; s < 64; s <<= 1) mx = fmaxf(mx, __shfl_xor(mx, s, 64));
  float e  = __expf(xn - mx);
  float se = e;
#pragma unroll
  for (int s = 1; s < 64; s <<= 1) se += __shfl_xor(se, s, 64);
  float lse = mx + __logf(se);
  int   t   = tgt[row];                 // wave-uniform
  float xt  = __shfl(xn, t, 64);
  if (lane == 0) {
    ce_row[row] = lse - xt;
    mp_key[row] = 0xFFFFFFFFu;          // +inf key for atomicMin
    mn_key[row] = 0u;                   // -inf key for atomicMax
  }
  if (blockIdx.x == 0 && threadIdx.x == 0) out[0] = 0.f;
}

// ---------------- Kernel B: MFMA similarity + pipelined hard mining ----------
// grid = 128 i-blocks * 16 j-splits = 2048 blocks of 256 threads (4 waves).
// R7 memory structure (4-tile phases, dbuf, XOR-swizzle) kept verbatim;
// compute restructured into an explicit 2-slot pipeline per phase:
//   jc0->slotB, mine carry(prev ph) | jc1->slotA, mine B(c0)
//   jc2->slotB, mine A(c1)          | jc3->slotA(carry), mine B(c2)
__global__ __launch_bounds__(256, 6)
void mine_kernel(const unsigned short* __restrict__ xb, const int* __restrict__ tgt,
                 unsigned* __restrict__ mp_key, unsigned* __restrict__ mn_key) {
  __shared__ unsigned short Bt[2][4][1024];   // 2 bufs x 4 tiles x 2KB, swizzled
  __shared__ unsigned short tjl[N_ROWS / 16]; // 2KB: targets of this j-range

  const int lane    = threadIdx.x & 63;
  const int wv      = threadIdx.x >> 6;
  const int iblk    = blockIdx.x >> 4;
  const int jspl    = blockIdx.x & 15;
  const int rowbase = iblk * 128 + wv * 32;
  const int m = lane & 15, q = lane >> 4;
  const int jbase = jspl * (N_ROWS / 16);

  // A fragments: lane holds row (rowbase+tr*16+m), k = q*8..q*8+7 (+32 for ks=1)
  bf16x8 a[2][2];
#pragma unroll
  for (int tr = 0; tr < 2; ++tr) {
    const unsigned short* p = xb + (rowbase + tr * 16 + m) * N_DIM + q * 8;
    a[tr][0] = *(const bf16x8*)(p);
    a[tr][1] = *(const bf16x8*)(p + 32);
  }
  int ti[2][4];
#pragma unroll
  for (int tr = 0; tr < 2; ++tr)
#pragma unroll
    for (int r = 0; r < 4; ++r)
      ti[tr][r] = tgt[rowbase + tr * 16 + q * 4 + r];

  float mp[8], mn[8];
#pragma unroll
  for (int k = 0; k < 8; ++k) { mp[k] = __builtin_inff(); mn[k] = -__builtin_inff(); }

  for (int k = threadIdx.x; k < N_ROWS / 16; k += 256)
    tjl[k] = (unsigned short)tgt[jbase + k];

  const unsigned short* src0 =
      xb + (jbase + (lane >> 3)) * N_DIM + (((lane & 7) ^ ((lane >> 3) & 7)) * 8);

#define STAGE(P_, BUF)                                                           \
  do {                                                                           \
    const unsigned short* s_ = src0 + ((P_) * 64 + wv * 16) * N_DIM;             \
    g2lds16(s_,             (unsigned short*)&Bt[(BUF)][wv][0] + lane * 8);      \
    g2lds16(s_ + 8 * N_DIM, (unsigned short*)&Bt[(BUF)][wv][0] + 512 + lane * 8);\
  } while (0)

  STAGE(0, 0);
  __syncthreads();

  const int roff0 = m * 128 + ((q * 16) ^ ((m & 7) << 4));
  const int roff1 = m * 128 + (((64) + q * 16) ^ ((m & 7) << 4));

// issue both MFMA pairs for one jc into D0/D1 (fresh accumulate from zero)
#define MFMA_JC(D0, D1, CB0, CB1)                                                \
  do {                                                                           \
    const f32x4 z_ = {0.f, 0.f, 0.f, 0.f};                                       \
    D0 = __builtin_amdgcn_mfma_f32_16x16x32_bf16(a[0][0], CB0, z_, 0, 0, 0);     \
    D0 = __builtin_amdgcn_mfma_f32_16x16x32_bf16(a[0][1], CB1, D0, 0, 0, 0);     \
    D1 = __builtin_amdgcn_mfma_f32_16x16x32_bf16(a[1][0], CB0, z_, 0, 0, 0);     \
    D1 = __builtin_amdgcn_mfma_f32_16x16x32_bf16(a[1][1], CB1, D1, 0, 0, 0);     \
  } while (0)

// ds_read + MFMA for tile J4 of current phase buffer; captures ctj into CTV
#define JC_STEP(J4, D0, D1, CTV)                                                 \
  do {                                                                           \
    const bf16x8 cb0_ = *(const bf16x8*)(bb + (J4) * 2048 + roff0);              \
    const bf16x8 cb1_ = *(const bf16x8*)(bb + (J4) * 2048 + roff1);              \
    CTV = (int)tjl[(ph * 4 + (J4)) * 16 + m];                                    \
    MFMA_JC(D0, D1, cb0_, cb1_);                                                 \
  } while (0)

// mine one jc's accumulators (5 VALU/elem) - runs under the NEXT jc's MFMA
#define MINE(A0, A1, CT)                                                         \
  do {                                                                           \
    _Pragma("unroll")                                                            \
    for (int r = 0; r < 4; ++r) {                                                \
      const bool p0 = ((CT) == ti[0][r]);                                        \
      mp[r] = fminf(mp[r], p0 ? (A0)[r] : __builtin_inff());                     \
      mn[r] = fmaxf(mn[r], p0 ? -__builtin_inff() : (A0)[r]);                    \
      const bool p1 = ((CT) == ti[1][r]);                                        \
      mp[4 + r] = fminf(mp[4 + r], p1 ? (A1)[r] : __builtin_inff());             \
      mn[4 + r] = fmaxf(mn[4 + r], p1 ? -__builtin_inff() : (A1)[r]);            \
    }                                                                            \
  } while (0)

  f32x4 pA0, pA1, qB0, qB1;
  int pctj = 0, c0, c1, c2;

#pragma unroll 1
  for (int ph = 0; ph < 16; ++ph) {
    const int pb = ph & 1;
    if (ph < 15) STAGE(ph + 1, pb ^ 1);
    const char* bb = (const char*)&Bt[pb][0][0];

    JC_STEP(0, qB0, qB1, c0);
    if (ph) MINE(pA0, pA1, pctj);        // carry from previous phase (reg-only)
    JC_STEP(1, pA0, pA1, c1);
    MINE(qB0, qB1, c0);
    JC_STEP(2, qB0, qB1, c2);
    MINE(pA0, pA1, c1);
    JC_STEP(3, pA0, pA1, pctj);          // carry out: pA = jc3, pctj = its ctj
    MINE(qB0, qB1, c2);

    __syncthreads();                     // publishes staged buffer for ph+1
  }
  MINE(pA0, pA1, pctj);                  // epilogue: last jc's accumulators
#undef MINE
#undef JC_STEP
#undef MFMA_JC
#undef STAGE

  // reduce across the 16 lanes (m = 0..15) inside each q-group
#pragma unroll
  for (int s = 1; s < 16; s <<= 1) {
#pragma unroll
    for (int k = 0; k < 8; ++k) {
      mp[k] = fminf(mp[k], __shfl_xor(mp[k], s, 64));
      mn[k] = fmaxf(mn[k], __shfl_xor(mn[k], s, 64));
    }
  }
  if (m == 0) {
#pragma unroll
    for (int tr = 0; tr < 2; ++tr)
#pragma unroll
      for (int r = 0; r < 4; ++r) {
        const int row = rowbase + tr * 16 + q * 4 + r;
        atomicMin(&mp_key[row], enc_key(mp[tr * 4 + r]));
        atomicMax(&mn_key[row], enc_key(mn[tr * 4 + r]));
      }
  }
}

// ---------------- Kernel C: final reduction (8 blocks, float atomicAdd) ------
__global__ void finalize_kernel(const unsigned* __restrict__ mp_key, const unsigned* __restrict__ mn_key,
                                const float* __restrict__ ce_row, float* __restrict__ out) {
  __shared__ float red[16];
  float s = 0.f;
#pragma unroll
  for (int it = 0; it < 2; ++it) {
    const int r = it * 8192 + blockIdx.x * 1024 + threadIdx.x;
    float ap = dec_key(mp_key[r]);
    float an = dec_key(mn_key[r]);
    s += fmaxf(0.5f + ap - an, 0.f) + fmaxf(0.8f - ap, 0.f) +
         fmaxf(an - 0.4f, 0.f) + ce_row[r];
  }
#pragma unroll
  for (int sh = 1; sh < 64; sh <<= 1) s += __shfl_xor(s, sh, 64);
  const int wv = threadIdx.x >> 6;
  if ((threadIdx.x & 63) == 0) red[wv] = s;
  __syncthreads();
  if (threadIdx.x == 0) {
    float t = 0.f;
#pragma unroll
    for (int w = 0; w < 16; ++w) t += red[w];
    atomicAdd(out, t * (1.0f / N_ROWS));
  }
}

extern "C" void kernel_launch(void* const* d_in, const int* in_sizes, int n_in,
                              void* d_out, int out_size, void* d_ws, size_t ws_size,
                              hipStream_t stream) {
  const float* x   = (const float*)d_in[0];
  const int*   tgt = (const int*)d_in[1];
  char* ws = (char*)d_ws;

  unsigned short* xb     = (unsigned short*)ws;                          // 2 MB bf16 normalized
  unsigned*       mp_key = (unsigned*)(ws + (2u << 20));                 // 64 KB
  unsigned*       mn_key = (unsigned*)(ws + (2u << 20) + (64u << 10));   // 64 KB
  float*          ce_row = (float*)(ws + (2u << 20) + (128u << 10));     // 64 KB
  float*          out    = (float*)d_out;

  prep_kernel<<<N_ROWS / 4, 256, 0, stream>>>(x, tgt, xb, ce_row, mp_key, mn_key, out);
  mine_kernel<<<(N_ROWS / 128) * 16, 256, 0, stream>>>(xb, tgt, mp_key, mn_key);
  finalize_kernel<<<8, 1024, 0, stream>>>(mp_key, mn_key, ce_row, out);
}